// Round 2
// baseline (187.793 us; speedup 1.0000x reference)
//
#include <hip/hip_runtime.h>
#include <hip/hip_bf16.h>
#include <math.h>

#define BB 32
#define NN 512

typedef _Float16 f16x8 __attribute__((ext_vector_type(8)));
typedef __fp16  fp16x2 __attribute__((ext_vector_type(2)));
typedef float f32x4 __attribute__((ext_vector_type(4)));

#define MFMA16(a, b, c) __builtin_amdgcn_mfma_f32_16x16x32_f16(a, b, c, 0, 0, 0)

union AF { f16x8 v; unsigned int u[4]; };

// async global->LDS, 16B per lane; LDS dest = wave-uniform base + lane*16
__device__ __forceinline__ void gload_lds16(const void* g, void* l) {
    __builtin_amdgcn_global_load_lds(
        (const __attribute__((address_space(1))) unsigned int*)g,
        (__attribute__((address_space(3))) unsigned int*)l, 16, 0, 0);
}

// ============ W^T fp16 prep (W0 + W1 fused), XOR-swizzled granules =========
// Stores logical granule g of row n at physical granule g^(n&7).
__global__ __launch_bounds__(256) void k_wt_prep(
    const float* __restrict__ W0, _Float16* __restrict__ W0T,
    const float* __restrict__ W1, _Float16* __restrict__ W1T)
{
    int id = blockIdx.x * 256 + threadIdx.x;   // 0..4607
    const float* W; _Float16* WT; int KT, task;
    if (id < 512) { W = W0; WT = W0T; KT = 64;  task = id; }
    else          { W = W1; WT = W1T; KT = 512; task = id - 512; }
    int n = task & 63, gabs = task >> 6;
    int c = gabs >> 3, g = gabs & 7;
    f16x8 hv;
#pragma unroll
    for (int e = 0; e < 8; ++e)
        hv[e] = (_Float16)W[(size_t)(gabs * 8 + e) * 64 + n];
    *(f16x8*)(WT + (size_t)n * KT + c * 64 + (g ^ (n & 7)) * 8) = hv;
}

// ============ per-(b,h): maxd = max_j dd; E=exp(dd-maxd), Eb=exp(.2(dd-maxd))
// Max-shifted tables keep every softmax factor <= 1 (no inf*0 path).
__global__ __launch_bounds__(256) void k_maxd(
    const float* __restrict__ dTg, float* __restrict__ maxd,
    float* __restrict__ E, float* __restrict__ Eb)
{
    __shared__ float sm[4];
    int bh = blockIdx.x;                       // 0..255
    int t = threadIdx.x, lane = t & 63, w = t >> 6;
    const float* p = dTg + (size_t)bh * NN;
    float d0 = p[t], d1 = p[t + 256];
    float m = fmaxf(d0, d1);
#pragma unroll
    for (int off = 32; off; off >>= 1) m = fmaxf(m, __shfl_xor(m, off));
    if (lane == 0) sm[w] = m;
    __syncthreads();
    float mx = fmaxf(fmaxf(sm[0], sm[1]), fmaxf(sm[2], sm[3]));
    if (t == 0) maxd[bh] = mx;
    float* Ep  = E  + (size_t)bh * NN;
    float* Ebp = Eb + (size_t)bh * NN;
    Ep[t]        = __expf(d0 - mx);
    Ep[t + 256]  = __expf(d1 - mx);
    Ebp[t]       = __expf(0.2f * (d0 - mx));
    Ebp[t + 256] = __expf(0.2f * (d1 - mx));
}

// ============ shared epilogue: 16x66 fp32 ctile -> s, dTg, fp16 hpT =========
static __device__ __forceinline__ void epi_sd_hpt(
    const float* ctile, const float* asd_f, int row0, int t,
    float* __restrict__ s, float* __restrict__ dTg, _Float16* __restrict__ hpT)
{
    int b = row0 >> 9, jb = row0 & 511;
    if (t < 128) {
        int rr = t >> 3, h = t & 7;
        float sv = 0.f, dv = 0.f;
#pragma unroll
        for (int f = 0; f < 64; ++f) {
            float hv = ctile[rr * 66 + f];
            sv = fmaf(hv, asd_f[f * 8 + h], sv);
            dv = fmaf(hv, asd_f[512 + f * 8 + h], dv);
        }
        s[((size_t)b * NN + jb + rr) * 8 + h] = sv;
        dTg[((size_t)b * 8 + h) * NN + jb + rr] = dv;
    } else {
        int t2 = t - 128;
        int f = t2 >> 1, jl = (t2 & 1) * 8;
        f16x8 hv;
#pragma unroll
        for (int e = 0; e < 8; ++e)
            hv[e] = (_Float16)ctile[(jl + e) * 66 + f];
        *(f16x8*)(hpT + ((size_t)b * 64 + f) * NN + jb + jl) = hv;
    }
}

// ============ Layer-0 GEMM + adj bit-mask prep ==============================
// GEMM: fp16 MFMA, 16 rows/block, K=64. Then the same block ballot-packs its
// 16 adj rows (self-loop folded in) into 1 bit/entry for the attn kernels.
__global__ __launch_bounds__(256) void k_gemm0(
    const float* __restrict__ x, const _Float16* __restrict__ W0T,
    const float* __restrict__ a_src, const float* __restrict__ a_dst,
    const float* __restrict__ adj, unsigned long long* __restrict__ adjb,
    float* __restrict__ s, float* __restrict__ dTg, _Float16* __restrict__ hpT)
{
    __shared__ float ctile[16 * 66];
    __shared__ float asd_f[1024];
    int t = threadIdx.x, row0 = blockIdx.x * 16;
    int lane = t & 63, w = t >> 6, cn = lane & 15, rq = lane >> 4;

    ((float4*)asd_f)[t] = (t < 128) ? ((const float4*)a_src)[t]
                                    : ((const float4*)a_dst)[t - 128];
    f32x4 acc;
#pragma unroll
    for (int e = 0; e < 4; ++e) acc[e] = 0.f;
#pragma unroll
    for (int ks = 0; ks < 2; ++ks) {
        const float* xp = x + (size_t)(row0 + cn) * 64 + ks * 32 + rq * 8;
        float4 x0 = *(const float4*)xp, x1 = *(const float4*)(xp + 4);
        f16x8 ah = {(_Float16)x0.x, (_Float16)x0.y, (_Float16)x0.z, (_Float16)x0.w,
                    (_Float16)x1.x, (_Float16)x1.y, (_Float16)x1.z, (_Float16)x1.w};
        int nn = w * 16 + cn;
        f16x8 bh = *(const f16x8*)(W0T + (size_t)nn * 64 + (((ks * 4 + rq) ^ (nn & 7)) * 8));
        acc = MFMA16(ah, bh, acc);
    }
#pragma unroll
    for (int r = 0; r < 4; ++r)
        ctile[(rq * 4 + r) * 66 + w * 16 + cn] = acc[r];
    __syncthreads();
    epi_sd_hpt(ctile, asd_f, row0, t, s, dTg, hpT);

    // ---- adj bitmask: wave w packs rows row0 + w*4 .. +3 (8 u64 each)
#pragma unroll
    for (int rl = 0; rl < 4; ++rl) {
        int gi = row0 + w * 4 + rl;            // global row (b*512 + i)
        int i = gi & (NN - 1);
        const float* ap = adj + (size_t)gi * NN;
#pragma unroll
        for (int jc8 = 0; jc8 < 8; ++jc8) {
            float v = ap[jc8 * 64 + lane];
            unsigned long long m = __ballot((v != 0.f) || (jc8 * 64 + lane == i));
            if (lane == 0) adjb[(size_t)gi * 8 + jc8] = m;
        }
    }
}

// ============ fused attention v6 ============================================
// P-build without transcendentals: exp(l-M) = e>=0 ? c0*E[j] : cb*Eb[j]
// with E=exp(dd-maxd), Eb=exp(0.2(dd-maxd)) precomputed per (b,h,j) and
// c0=exp(sv+maxd-M), cb=exp(0.2(sv+maxd)-M) per row (all factors <= 1).
// adj as 1-bit mask (u64/chunk). hT staged via global_load_lds double-buffer
// (pre-swizzled source, linear LDS dest) -> 1 barrier per 64-j chunk.
// Same staging for gemm1's W1T ping/pong.
template<int MODE>
__global__ __launch_bounds__(256, 4) void k_attn_fused(
    const unsigned long long* __restrict__ adjb, const float* __restrict__ s,
    const float* __restrict__ dTg, const float* __restrict__ maxd,
    const float* __restrict__ E, const float* __restrict__ Eb,
    const _Float16* __restrict__ hpT,
    const _Float16* __restrict__ W1T,
    const float* __restrict__ a_src, const float* __restrict__ a_dst,
    float* __restrict__ s_out, float* __restrict__ dTg_out,
    _Float16* __restrict__ hpT_out, float* __restrict__ o_f)
{
    __shared__ __align__(16) char smem[32768];
    _Float16* hTd0 = (_Float16*)smem;          // [64][64] swizzled fp16, 8KB
    _Float16* hTd1 = (_Float16*)(smem + 8192); // double buffer

    int blk = blockIdx.x;
    int vb = ((blk & 7) << 7) | (blk >> 3);    // XCD swizzle: 4 batches/XCD
    int b = vb >> 5, i0 = (vb & 31) << 4;
    int row0 = vb * 16;                        // = b*512 + i0
    int t = threadIdx.x, lane = t & 63, w = t >> 6;
    int cn = lane & 15, rq = lane >> 4;
    int h0 = 2 * w, h1 = h0 + 1;
    int myrow = i0 + cn;

    const _Float16* hb = hpT + (size_t)b * 64 * NN;

    // staging geometry: source pre-swizzled (granule g0^(f&7)), LDS linear
    int f0 = t >> 3, g0 = t & 7;               // f0 in [0,32)
    const _Float16* src0 = hb + (size_t)f0 * NN + ((g0 ^ (f0 & 7)) * 8);
    const _Float16* src1 = hb + (size_t)(f0 + 32) * NN + ((g0 ^ (f0 & 7)) * 8);
    {   // prologue: stage chunk 0 into buf0
        _Float16* db = hTd0 + (w << 9);
        gload_lds16(src0, db);
        gload_lds16(src1, db + 2048);
    }

    float sv0 = s[((size_t)b * NN + myrow) * 8 + h0];
    float sv1 = s[((size_t)b * NN + myrow) * 8 + h1];
    float md0 = maxd[b * 8 + h0], md1 = maxd[b * 8 + h1];
    float M0 = fmaxf(sv0 + md0, 0.f);
    float M1 = fmaxf(sv1 + md1, 0.f);
    float c00 = __expf(sv0 + md0 - M0), cb0 = __expf(0.2f * (sv0 + md0) - M0);
    float c01 = __expf(sv1 + md1 - M1), cb1 = __expf(0.2f * (sv1 + md1) - M1);

    const float* dg0  = dTg + ((size_t)b * 8 + h0) * NN;
    const float* dg1  = dTg + ((size_t)b * 8 + h1) * NN;
    const float* Er0  = E   + ((size_t)b * 8 + h0) * NN;
    const float* Er1  = E   + ((size_t)b * 8 + h1) * NN;
    const float* Ebr0 = Eb  + ((size_t)b * 8 + h0) * NN;
    const float* Ebr1 = Eb  + ((size_t)b * 8 + h1) * NN;
    const unsigned long long* abr = adjb + ((size_t)b * NN + myrow) * 8;
    int rq8 = rq * 8;

    f16x8 ones;
#pragma unroll
    for (int e = 0; e < 8; ++e) ones[e] = (_Float16)1.0f;

    f32x4 acc[2][4], accrs[2];
#pragma unroll
    for (int hh = 0; hh < 2; ++hh) {
#pragma unroll
        for (int e = 0; e < 4; ++e) accrs[hh][e] = 0.f;
#pragma unroll
        for (int ft = 0; ft < 4; ++ft)
#pragma unroll
            for (int e = 0; e < 4; ++e) acc[hh][ft][e] = 0.f;
    }

    unsigned long long mb = abr[0];
    __syncthreads();                           // buf0 staged

#pragma unroll 2
    for (int jcx = 0; jcx < 8; ++jcx) {
        int jc = jcx * 64;
        const _Float16* hTc = (jcx & 1) ? hTd1 : hTd0;
        if (jcx < 7) {                         // stage NEXT chunk into idle buf
            _Float16* db = ((jcx & 1) ? hTd0 : hTd1) + (w << 9);
            gload_lds16(src0 + jc + 64, db);
            gload_lds16(src1 + jc + 64, db + 2048);
        }
        unsigned long long mbn = (jcx < 7) ? abr[jcx + 1] : 0ull;
        unsigned int ml = (unsigned int)mb, mhh = (unsigned int)(mb >> 32);
#pragma unroll
        for (int ks = 0; ks < 2; ++ks) {
            int j0 = jc + ks * 32 + rq8;
            unsigned int mby = ((ks ? mhh : ml) >> rq8) & 0xffu;
            float dd0[8], dd1[8], Ev0[8], Ev1[8], Eb0v[8], Eb1v[8];
            *(float4*)&dd0[0]  = *(const float4*)(dg0 + j0);
            *(float4*)&dd0[4]  = *(const float4*)(dg0 + j0 + 4);
            *(float4*)&dd1[0]  = *(const float4*)(dg1 + j0);
            *(float4*)&dd1[4]  = *(const float4*)(dg1 + j0 + 4);
            *(float4*)&Ev0[0]  = *(const float4*)(Er0 + j0);
            *(float4*)&Ev0[4]  = *(const float4*)(Er0 + j0 + 4);
            *(float4*)&Ev1[0]  = *(const float4*)(Er1 + j0);
            *(float4*)&Ev1[4]  = *(const float4*)(Er1 + j0 + 4);
            *(float4*)&Eb0v[0] = *(const float4*)(Ebr0 + j0);
            *(float4*)&Eb0v[4] = *(const float4*)(Ebr0 + j0 + 4);
            *(float4*)&Eb1v[0] = *(const float4*)(Ebr1 + j0);
            *(float4*)&Eb1v[4] = *(const float4*)(Ebr1 + j0 + 4);
            AF aA, aB;
#pragma unroll
            for (int e = 0; e < 8; e += 2) {
                float pA[2], pB[2];
#pragma unroll
                for (int q = 0; q < 2; ++q) {
                    int ee = e + q;
                    bool con = (mby >> ee) & 1u;
                    float e0 = sv0 + dd0[ee];
                    float p0 = (e0 >= 0.f) ? c00 * Ev0[ee] : cb0 * Eb0v[ee];
                    pA[q] = (con && e0 != 0.f) ? p0 : 0.f;   // mask + ==0 quirk
                    float e1 = sv1 + dd1[ee];
                    float p1 = (e1 >= 0.f) ? c01 * Ev1[ee] : cb1 * Eb1v[ee];
                    pB[q] = (con && e1 != 0.f) ? p1 : 0.f;
                }
                fp16x2 ka = __builtin_amdgcn_cvt_pkrtz(pA[0], pA[1]);
                fp16x2 kb = __builtin_amdgcn_cvt_pkrtz(pB[0], pB[1]);
                aA.u[e >> 1] = __builtin_bit_cast(unsigned int, ka);
                aB.u[e >> 1] = __builtin_bit_cast(unsigned int, kb);
            }
            accrs[0] = MFMA16(aA.v, ones, accrs[0]);
            accrs[1] = MFMA16(aB.v, ones, accrs[1]);
#pragma unroll
            for (int ft = 0; ft < 4; ++ft) {
                int f = ft * 16 + cn;
                f16x8 bh = *(const f16x8*)&hTc[f * 64 + (((ks * 4 + rq) ^ (f & 7)) * 8)];
                acc[0][ft] = MFMA16(aA.v, bh, acc[0][ft]);
                acc[1][ft] = MFMA16(aB.v, bh, acc[1][ft]);
            }
        }
        mb = mbn;
        __syncthreads();                       // drains next-chunk staging too
    }

    float invr[2][4];
#pragma unroll
    for (int hh = 0; hh < 2; ++hh)
#pragma unroll
        for (int r = 0; r < 4; ++r) invr[hh][r] = 1.0f / accrs[hh][r];

    if (MODE == 0) {
        // ---- stage gemm1's kc=0 B-tile early (hT buffers dead after loop)
        _Float16* Bst0 = (_Float16*)smem;
        _Float16* Bst1 = (_Float16*)(smem + 8192);
        const _Float16* wsrc = W1T + (size_t)(t >> 3) * 512 + ((t & 7) * 8);
        {
            _Float16* db = Bst0 + (w << 9);
            gload_lds16(wsrc, db);
            gload_lds16(wsrc + 32 * 512, db + 2048);
        }
        // ---- x1 tiles (normalized + ELU) into LDS, A-layout, XOR-swizzled
        _Float16* x1all = (_Float16*)(smem + 16384);   // [8 heads][16*64], 16KB
#pragma unroll
        for (int hh = 0; hh < 2; ++hh) {
            int h = h0 + hh;
#pragma unroll
            for (int ft = 0; ft < 4; ++ft)
#pragma unroll
                for (int r = 0; r < 4; ++r) {
                    int il = rq * 4 + r;
                    float v = acc[hh][ft][r] * invr[hh][r];
                    v = v > 0.f ? v : __expf(v) - 1.f;   // ELU
                    int f = ft * 16 + cn;
                    x1all[h * 1024 + il * 64 + (((f >> 3) ^ (il & 7)) * 8) + (f & 7)] =
                        (_Float16)v;
                }
        }
        __syncthreads();   // x1all visible + Bst0 staged
        f32x4 g1;
#pragma unroll
        for (int e = 0; e < 4; ++e) g1[e] = 0.f;
        for (int kc = 0; kc < 8; ++kc) {
            const _Float16* Bc = (kc & 1) ? Bst1 : Bst0;
            if (kc < 7) {   // stage next chunk into the idle buffer
                _Float16* db = ((kc & 1) ? Bst0 : Bst1) + (w << 9);
                gload_lds16(wsrc + (kc + 1) * 64, db);
                gload_lds16(wsrc + 32 * 512 + (kc + 1) * 64, db + 2048);
            }
#pragma unroll
            for (int ks = 0; ks < 2; ++ks) {
                int pa = (((ks * 4 + rq) ^ (cn & 7)) * 8);
                f16x8 ah = *(const f16x8*)&x1all[kc * 1024 + cn * 64 + pa];
                int nn = w * 16 + cn;
                f16x8 bh = *(const f16x8*)&Bc[nn * 64 + (((ks * 4 + rq) ^ (nn & 7)) * 8)];
                g1 = MFMA16(ah, bh, g1);
            }
            __syncthreads();
        }
        float* ctile = (float*)(smem + 16384); // 4224 B (x1all dead)
        float* asd_f = (float*)(smem + 24576); // 4096 B
#pragma unroll
        for (int r = 0; r < 4; ++r)
            ctile[(rq * 4 + r) * 66 + w * 16 + cn] = g1[r];
        ((float4*)asd_f)[t] = (t < 128) ? ((const float4*)a_src)[t]
                                        : ((const float4*)a_dst)[t - 128];
        __syncthreads();
        epi_sd_hpt(ctile, asd_f, row0, t, s_out, dTg_out, hpT_out);
    } else {
        float* red = (float*)smem;             // [4][16][64] fp32 = 16 KB
#pragma unroll
        for (int ft = 0; ft < 4; ++ft)
#pragma unroll
            for (int r = 0; r < 4; ++r) {
                int il = rq * 4 + r;
                float v = acc[0][ft][r] * invr[0][r]
                        + acc[1][ft][r] * invr[1][r];
                red[(w * 16 + il) * 64 + ft * 16 + cn] = v;
            }
        __syncthreads();
#pragma unroll
        for (int u = 0; u < 4; ++u) {
            int idx = t + u * 256;
            int il = idx >> 6, f = idx & 63;
            float sum = red[il * 64 + f] + red[(16 + il) * 64 + f]
                      + red[(32 + il) * 64 + f] + red[(48 + il) * 64 + f];
            o_f[((size_t)b * NN + i0 + il) * 64 + f] = sum * 0.125f;
        }
    }
}

extern "C" void kernel_launch(void* const* d_in, const int* in_sizes, int n_in,
                              void* d_out, int out_size, void* d_ws, size_t ws_size,
                              hipStream_t stream) {
    const float* x      = (const float*)d_in[0];
    const float* adj    = (const float*)d_in[1];
    const float* W0     = (const float*)d_in[4];
    const float* a_src0 = (const float*)d_in[5];
    const float* a_dst0 = (const float*)d_in[6];
    const float* W1     = (const float*)d_in[7];
    const float* a_src1 = (const float*)d_in[8];
    const float* a_dst1 = (const float*)d_in[9];
    float* out = (float*)d_out;

    float* ws = (float*)d_ws;
    const size_t R = (size_t)BB * NN;            // 16384 rows
    const size_t BHN = (size_t)BB * 8 * NN;      // 131072
    float* s0    = ws;                           // R*8
    float* dTg0  = s0 + R * 8;
    float* s1    = dTg0 + BHN;
    float* dTg1  = s1 + R * 8;
    float* maxd0 = dTg1 + BHN;                   // 256
    float* maxd1 = maxd0 + 256;                  // 256
    float* E0    = maxd1 + 256;                  // BHN each
    float* Eb0   = E0 + BHN;
    float* E1    = Eb0 + BHN;
    float* Eb1   = E1 + BHN;
    _Float16* hp0T = (_Float16*)(Eb1 + BHN);     // 32*64*512
    _Float16* hp1T = hp0T + (size_t)BB * 64 * NN;
    _Float16* W0T  = hp1T + (size_t)BB * 64 * NN;   // 64*64
    _Float16* W1T  = W0T + (size_t)64 * 64;         // 64*512
    unsigned long long* adjb = (unsigned long long*)(W1T + (size_t)64 * 512); // 16384*8B

    k_wt_prep<<<18, 256, 0, stream>>>(W0, W0T, W1, W1T);
    k_gemm0<<<1024, 256, 0, stream>>>(x, W0T, a_src0, a_dst0, adj, adjb,
                                      s0, dTg0, hp0T);
    k_maxd<<<256, 256, 0, stream>>>(dTg0, maxd0, E0, Eb0);
    k_attn_fused<0><<<1024, 256, 0, stream>>>(adjb, s0, dTg0, maxd0, E0, Eb0,
                                              hp0T, W1T, a_src1, a_dst1,
                                              s1, dTg1, hp1T, nullptr);
    k_maxd<<<256, 256, 0, stream>>>(dTg1, maxd1, E1, Eb1);
    k_attn_fused<1><<<1024, 256, 0, stream>>>(adjb, s1, dTg1, maxd1, E1, Eb1,
                                              hp1T, nullptr, nullptr, nullptr,
                                              nullptr, nullptr, nullptr, out);
}

// Round 3
// 159.710 us; speedup vs baseline: 1.1758x; 1.1758x over previous
//
#include <hip/hip_runtime.h>
#include <hip/hip_bf16.h>
#include <math.h>

#define BB 32
#define NN 512

typedef _Float16 f16x8 __attribute__((ext_vector_type(8)));
typedef __fp16  fp16x2 __attribute__((ext_vector_type(2)));
typedef float f32x4 __attribute__((ext_vector_type(4)));

#define MFMA16(a, b, c) __builtin_amdgcn_mfma_f32_16x16x32_f16(a, b, c, 0, 0, 0)

union AF { f16x8 v; unsigned int u[4]; };

// async global->LDS, 16B per lane; LDS dest = wave-uniform base + lane*16
__device__ __forceinline__ void gload_lds16(const void* g, void* l) {
    __builtin_amdgcn_global_load_lds(
        (const __attribute__((address_space(1))) unsigned int*)g,
        (__attribute__((address_space(3))) unsigned int*)l, 16, 0, 0);
}

// ============ W^T fp16 prep (W0 + W1 fused), XOR-swizzled granules =========
// Stores logical granule g of row n at physical granule g^(n&7).
__global__ __launch_bounds__(256) void k_wt_prep(
    const float* __restrict__ W0, _Float16* __restrict__ W0T,
    const float* __restrict__ W1, _Float16* __restrict__ W1T)
{
    int id = blockIdx.x * 256 + threadIdx.x;   // 0..4607
    const float* W; _Float16* WT; int KT, task;
    if (id < 512) { W = W0; WT = W0T; KT = 64;  task = id; }
    else          { W = W1; WT = W1T; KT = 512; task = id - 512; }
    int n = task & 63, gabs = task >> 6;
    int c = gabs >> 3, g = gabs & 7;
    f16x8 hv;
#pragma unroll
    for (int e = 0; e < 8; ++e)
        hv[e] = (_Float16)W[(size_t)(gabs * 8 + e) * 64 + n];
    *(f16x8*)(WT + (size_t)n * KT + c * 64 + (g ^ (n & 7)) * 8) = hv;
}

// ============ per-(b,h) max over j of dTg[b][h][j] ==========================
__global__ __launch_bounds__(256) void k_maxd(
    const float* __restrict__ dTg, float* __restrict__ maxd)
{
    __shared__ float sm[4];
    int bh = blockIdx.x;                       // 0..255
    int t = threadIdx.x, lane = t & 63, w = t >> 6;
    const float* p = dTg + (size_t)bh * NN;
    float m = fmaxf(p[t], p[t + 256]);
#pragma unroll
    for (int off = 32; off; off >>= 1) m = fmaxf(m, __shfl_xor(m, off));
    if (lane == 0) sm[w] = m;
    __syncthreads();
    if (t == 0) maxd[bh] = fmaxf(fmaxf(sm[0], sm[1]), fmaxf(sm[2], sm[3]));
}

// ============ shared epilogue: 16x66 fp32 ctile -> s, dTg, fp16 hpT =========
static __device__ __forceinline__ void epi_sd_hpt(
    const float* ctile, const float* asd_f, int row0, int t,
    float* __restrict__ s, float* __restrict__ dTg, _Float16* __restrict__ hpT)
{
    int b = row0 >> 9, jb = row0 & 511;
    if (t < 128) {
        int rr = t >> 3, h = t & 7;
        float sv = 0.f, dv = 0.f;
#pragma unroll
        for (int f = 0; f < 64; ++f) {
            float hv = ctile[rr * 66 + f];
            sv = fmaf(hv, asd_f[f * 8 + h], sv);
            dv = fmaf(hv, asd_f[512 + f * 8 + h], dv);
        }
        s[((size_t)b * NN + jb + rr) * 8 + h] = sv;
        dTg[((size_t)b * 8 + h) * NN + jb + rr] = dv;
    } else {
        int t2 = t - 128;
        int f = t2 >> 1, jl = (t2 & 1) * 8;
        f16x8 hv;
#pragma unroll
        for (int e = 0; e < 8; ++e)
            hv[e] = (_Float16)ctile[(jl + e) * 66 + f];
        *(f16x8*)(hpT + ((size_t)b * 64 + f) * NN + jb + jl) = hv;
    }
}

// ============ Layer-0 GEMM + adj bit-mask prep (vectorized) =================
// adj loads (float4) issue at kernel top, overlap the GEMM; bits packed via
// a small LDS u32 tile, assembled into u64 rows.
__global__ __launch_bounds__(256) void k_gemm0(
    const float* __restrict__ x, const _Float16* __restrict__ W0T,
    const float* __restrict__ a_src, const float* __restrict__ a_dst,
    const float* __restrict__ adj, unsigned long long* __restrict__ adjb,
    float* __restrict__ s, float* __restrict__ dTg, _Float16* __restrict__ hpT)
{
    __shared__ float ctile[16 * 66];
    __shared__ float asd_f[1024];
    __shared__ unsigned int mrow[16][16];
    int t = threadIdx.x, row0 = blockIdx.x * 16;
    int lane = t & 63, w = t >> 6, cn = lane & 15, rq = lane >> 4;

    // ---- issue adj loads early: thread t covers row (t>>4), j in [seg*32,+32)
    int ar = t >> 4, seg = t & 15;
    const float* ap = adj + (size_t)(row0 + ar) * NN + seg * 32;
    float4 av[8];
#pragma unroll
    for (int q = 0; q < 8; ++q) av[q] = ((const float4*)ap)[q];

    ((float4*)asd_f)[t] = (t < 128) ? ((const float4*)a_src)[t]
                                    : ((const float4*)a_dst)[t - 128];
    f32x4 acc;
#pragma unroll
    for (int e = 0; e < 4; ++e) acc[e] = 0.f;
#pragma unroll
    for (int ks = 0; ks < 2; ++ks) {
        const float* xp = x + (size_t)(row0 + cn) * 64 + ks * 32 + rq * 8;
        float4 x0 = *(const float4*)xp, x1 = *(const float4*)(xp + 4);
        f16x8 ah = {(_Float16)x0.x, (_Float16)x0.y, (_Float16)x0.z, (_Float16)x0.w,
                    (_Float16)x1.x, (_Float16)x1.y, (_Float16)x1.z, (_Float16)x1.w};
        int nn = w * 16 + cn;
        f16x8 bh = *(const f16x8*)(W0T + (size_t)nn * 64 + (((ks * 4 + rq) ^ (nn & 7)) * 8));
        acc = MFMA16(ah, bh, acc);
    }
#pragma unroll
    for (int r = 0; r < 4; ++r)
        ctile[(rq * 4 + r) * 66 + w * 16 + cn] = acc[r];
    __syncthreads();
    epi_sd_hpt(ctile, asd_f, row0, t, s, dTg, hpT);

    // ---- pack 32 adj entries -> u32 bits, fold self-loop, assemble u64s
    unsigned int m32 = 0;
#pragma unroll
    for (int q = 0; q < 8; ++q) {
        if (av[q].x != 0.f) m32 |= 1u << (q * 4 + 0);
        if (av[q].y != 0.f) m32 |= 1u << (q * 4 + 1);
        if (av[q].z != 0.f) m32 |= 1u << (q * 4 + 2);
        if (av[q].w != 0.f) m32 |= 1u << (q * 4 + 3);
    }
    int i = (row0 + ar) & (NN - 1);
    if ((i >> 5) == seg) m32 |= 1u << (i & 31);
    mrow[ar][seg] = m32;
    __syncthreads();
    if (t < 128) {
        int r = t >> 3, k = t & 7;
        unsigned long long u = (unsigned long long)mrow[r][2 * k]
                             | ((unsigned long long)mrow[r][2 * k + 1] << 32);
        adjb[(size_t)(row0 + r) * 8 + k] = u;
    }
}

// ============ fused attention v7 ============================================
// exp-inline P-build (round-0 math, bitwise identical) + dd loads software-
// pipelined one ks-step ahead (A/B register sets). adj as 1-bit mask.
// hT staged via global_load_lds double-buffer (pre-swizzled source, linear
// LDS dest) -> 1 barrier per 64-j chunk. Same staging for gemm1's W1T.
#define LD8(DST0, DST1, J)                                              \
    do {                                                                \
        *(float4*)&DST0[0] = *(const float4*)(dg0 + (J));               \
        *(float4*)&DST0[4] = *(const float4*)(dg0 + (J) + 4);           \
        *(float4*)&DST1[0] = *(const float4*)(dg1 + (J));               \
        *(float4*)&DST1[4] = *(const float4*)(dg1 + (J) + 4);           \
    } while (0)

#define PSTEP(DD0v, DD1v, MBYTE, KS, HTC)                               \
    do {                                                                \
        AF aA, aB;                                                      \
        _Pragma("unroll")                                               \
        for (int e = 0; e < 8; e += 2) {                                \
            float pA[2], pB[2];                                         \
            _Pragma("unroll")                                           \
            for (int q = 0; q < 2; ++q) {                               \
                int ee = e + q;                                         \
                bool con = (MBYTE >> ee) & 1u;                          \
                float e0 = sv0 + DD0v[ee];                              \
                float l0 = fmaxf(e0, 0.2f * e0);                        \
                float p0 = __expf(l0 - M0);                             \
                pA[q] = (con && l0 != 0.f) ? p0 : 0.f;                  \
                float e1 = sv1 + DD1v[ee];                              \
                float l1 = fmaxf(e1, 0.2f * e1);                        \
                float p1 = __expf(l1 - M1);                             \
                pB[q] = (con && l1 != 0.f) ? p1 : 0.f;                  \
            }                                                           \
            fp16x2 ka = __builtin_amdgcn_cvt_pkrtz(pA[0], pA[1]);       \
            fp16x2 kb = __builtin_amdgcn_cvt_pkrtz(pB[0], pB[1]);       \
            aA.u[e >> 1] = __builtin_bit_cast(unsigned int, ka);        \
            aB.u[e >> 1] = __builtin_bit_cast(unsigned int, kb);        \
        }                                                               \
        accrs[0] = MFMA16(aA.v, ones, accrs[0]);                        \
        accrs[1] = MFMA16(aB.v, ones, accrs[1]);                        \
        _Pragma("unroll")                                               \
        for (int ft = 0; ft < 4; ++ft) {                                \
            int f = ft * 16 + cn;                                       \
            f16x8 bh = *(const f16x8*)&HTC[f * 64 + ((((KS) * 4 + rq) ^ (f & 7)) * 8)]; \
            acc[0][ft] = MFMA16(aA.v, bh, acc[0][ft]);                  \
            acc[1][ft] = MFMA16(aB.v, bh, acc[1][ft]);                  \
        }                                                               \
    } while (0)

template<int MODE>
__global__ __launch_bounds__(256, 4) void k_attn_fused(
    const unsigned long long* __restrict__ adjb, const float* __restrict__ s,
    const float* __restrict__ dTg, const float* __restrict__ maxd,
    const _Float16* __restrict__ hpT,
    const _Float16* __restrict__ W1T,
    const float* __restrict__ a_src, const float* __restrict__ a_dst,
    float* __restrict__ s_out, float* __restrict__ dTg_out,
    _Float16* __restrict__ hpT_out, float* __restrict__ o_f)
{
    __shared__ __align__(16) char smem[32768];
    _Float16* hTd0 = (_Float16*)smem;          // [64][64] swizzled fp16, 8KB
    _Float16* hTd1 = (_Float16*)(smem + 8192); // double buffer

    int blk = blockIdx.x;
    int vb = ((blk & 7) << 7) | (blk >> 3);    // XCD swizzle: 4 batches/XCD
    int b = vb >> 5, i0 = (vb & 31) << 4;
    int row0 = vb * 16;                        // = b*512 + i0
    int t = threadIdx.x, lane = t & 63, w = t >> 6;
    int cn = lane & 15, rq = lane >> 4;
    int h0 = 2 * w, h1 = h0 + 1;
    int myrow = i0 + cn;

    const _Float16* hb = hpT + (size_t)b * 64 * NN;

    // staging geometry: source pre-swizzled (granule g0^(f&7)), LDS linear
    int f0 = t >> 3, g0 = t & 7;               // f0 in [0,32)
    const _Float16* src0 = hb + (size_t)f0 * NN + ((g0 ^ (f0 & 7)) * 8);
    const _Float16* src1 = hb + (size_t)(f0 + 32) * NN + ((g0 ^ (f0 & 7)) * 8);
    {   // prologue: stage chunk 0 into buf0
        _Float16* db = hTd0 + (w << 9);
        gload_lds16(src0, db);
        gload_lds16(src1, db + 2048);
    }

    float sv0 = s[((size_t)b * NN + myrow) * 8 + h0];
    float sv1 = s[((size_t)b * NN + myrow) * 8 + h1];
    float M0 = fmaxf(sv0 + maxd[b * 8 + h0], 0.f);
    float M1 = fmaxf(sv1 + maxd[b * 8 + h1], 0.f);

    const float* dg0 = dTg + ((size_t)b * 8 + h0) * NN;
    const float* dg1 = dTg + ((size_t)b * 8 + h1) * NN;
    const unsigned long long* abr = adjb + ((size_t)b * NN + myrow) * 8;
    int rq8 = rq * 8;

    f16x8 ones;
#pragma unroll
    for (int e = 0; e < 8; ++e) ones[e] = (_Float16)1.0f;

    f32x4 acc[2][4], accrs[2];
#pragma unroll
    for (int hh = 0; hh < 2; ++hh) {
#pragma unroll
        for (int e = 0; e < 4; ++e) accrs[hh][e] = 0.f;
#pragma unroll
        for (int ft = 0; ft < 4; ++ft)
#pragma unroll
            for (int e = 0; e < 4; ++e) acc[hh][ft][e] = 0.f;
    }

    // software pipeline: A holds current step's dd, B the prefetched next step
    float ddA0[8], ddA1[8], ddB0[8], ddB1[8];
    unsigned long long mb = abr[0];
    LD8(ddA0, ddA1, rq8);                      // step 0 (jc=0, ks=0)
    __syncthreads();                           // buf0 staged

    for (int jcx = 0; jcx < 8; ++jcx) {
        int jc = jcx * 64;
        const _Float16* hTc = (jcx & 1) ? hTd1 : hTd0;
        if (jcx < 7) {                         // stage NEXT chunk into idle buf
            _Float16* db = ((jcx & 1) ? hTd0 : hTd1) + (w << 9);
            gload_lds16(src0 + jc + 64, db);
            gload_lds16(src1 + jc + 64, db + 2048);
        }
        unsigned long long mbn = (jcx < 7) ? abr[jcx + 1] : 0ull;
        unsigned int ml = (unsigned int)mb, mhh = (unsigned int)(mb >> 32);
        // ks=0: prefetch B (this chunk's second half), compute A
        LD8(ddB0, ddB1, jc + 32 + rq8);
        {
            unsigned int mby = (ml >> rq8) & 0xffu;
            PSTEP(ddA0, ddA1, mby, 0, hTc);
        }
        // ks=1: prefetch A (next chunk's first half), compute B
        if (jcx < 7) LD8(ddA0, ddA1, jc + 64 + rq8);
        {
            unsigned int mby = (mhh >> rq8) & 0xffu;
            PSTEP(ddB0, ddB1, mby, 1, hTc);
        }
        mb = mbn;
        __syncthreads();                       // drains next-chunk staging too
    }

    float invr[2][4];
#pragma unroll
    for (int hh = 0; hh < 2; ++hh)
#pragma unroll
        for (int r = 0; r < 4; ++r) invr[hh][r] = 1.0f / accrs[hh][r];

    if (MODE == 0) {
        // ---- stage gemm1's kc=0 B-tile early (hT buffers dead after loop)
        _Float16* Bst0 = (_Float16*)smem;
        _Float16* Bst1 = (_Float16*)(smem + 8192);
        const _Float16* wsrc = W1T + (size_t)(t >> 3) * 512 + ((t & 7) * 8);
        {
            _Float16* db = Bst0 + (w << 9);
            gload_lds16(wsrc, db);
            gload_lds16(wsrc + 32 * 512, db + 2048);
        }
        // ---- x1 tiles (normalized + ELU) into LDS, A-layout, XOR-swizzled
        _Float16* x1all = (_Float16*)(smem + 16384);   // [8 heads][16*64], 16KB
#pragma unroll
        for (int hh = 0; hh < 2; ++hh) {
            int h = h0 + hh;
#pragma unroll
            for (int ft = 0; ft < 4; ++ft)
#pragma unroll
                for (int r = 0; r < 4; ++r) {
                    int il = rq * 4 + r;
                    float v = acc[hh][ft][r] * invr[hh][r];
                    v = v > 0.f ? v : __expf(v) - 1.f;   // ELU
                    int f = ft * 16 + cn;
                    x1all[h * 1024 + il * 64 + (((f >> 3) ^ (il & 7)) * 8) + (f & 7)] =
                        (_Float16)v;
                }
        }
        __syncthreads();   // x1all visible + Bst0 staged
        f32x4 g1;
#pragma unroll
        for (int e = 0; e < 4; ++e) g1[e] = 0.f;
        for (int kc = 0; kc < 8; ++kc) {
            const _Float16* Bc = (kc & 1) ? Bst1 : Bst0;
            if (kc < 7) {   // stage next chunk into the idle buffer
                _Float16* db = ((kc & 1) ? Bst0 : Bst1) + (w << 9);
                gload_lds16(wsrc + (kc + 1) * 64, db);
                gload_lds16(wsrc + 32 * 512 + (kc + 1) * 64, db + 2048);
            }
#pragma unroll
            for (int ks = 0; ks < 2; ++ks) {
                int pa = (((ks * 4 + rq) ^ (cn & 7)) * 8);
                f16x8 ah = *(const f16x8*)&x1all[kc * 1024 + cn * 64 + pa];
                int nn = w * 16 + cn;
                f16x8 bh = *(const f16x8*)&Bc[nn * 64 + (((ks * 4 + rq) ^ (nn & 7)) * 8)];
                g1 = MFMA16(ah, bh, g1);
            }
            __syncthreads();
        }
        float* ctile = (float*)(smem + 16384); // 4224 B (x1all dead)
        float* asd_f = (float*)(smem + 24576); // 4096 B
#pragma unroll
        for (int r = 0; r < 4; ++r)
            ctile[(rq * 4 + r) * 66 + w * 16 + cn] = g1[r];
        ((float4*)asd_f)[t] = (t < 128) ? ((const float4*)a_src)[t]
                                        : ((const float4*)a_dst)[t - 128];
        __syncthreads();
        epi_sd_hpt(ctile, asd_f, row0, t, s_out, dTg_out, hpT_out);
    } else {
        float* red = (float*)smem;             // [4][16][64] fp32 = 16 KB
#pragma unroll
        for (int ft = 0; ft < 4; ++ft)
#pragma unroll
            for (int r = 0; r < 4; ++r) {
                int il = rq * 4 + r;
                float v = acc[0][ft][r] * invr[0][r]
                        + acc[1][ft][r] * invr[1][r];
                red[(w * 16 + il) * 64 + ft * 16 + cn] = v;
            }
        __syncthreads();
#pragma unroll
        for (int u = 0; u < 4; ++u) {
            int idx = t + u * 256;
            int il = idx >> 6, f = idx & 63;
            float sum = red[il * 64 + f] + red[(16 + il) * 64 + f]
                      + red[(32 + il) * 64 + f] + red[(48 + il) * 64 + f];
            o_f[((size_t)b * NN + i0 + il) * 64 + f] = sum * 0.125f;
        }
    }
}

extern "C" void kernel_launch(void* const* d_in, const int* in_sizes, int n_in,
                              void* d_out, int out_size, void* d_ws, size_t ws_size,
                              hipStream_t stream) {
    const float* x      = (const float*)d_in[0];
    const float* adj    = (const float*)d_in[1];
    const float* W0     = (const float*)d_in[4];
    const float* a_src0 = (const float*)d_in[5];
    const float* a_dst0 = (const float*)d_in[6];
    const float* W1     = (const float*)d_in[7];
    const float* a_src1 = (const float*)d_in[8];
    const float* a_dst1 = (const float*)d_in[9];
    float* out = (float*)d_out;

    float* ws = (float*)d_ws;
    const size_t R = (size_t)BB * NN;            // 16384 rows
    const size_t BHN = (size_t)BB * 8 * NN;      // 131072
    float* s0    = ws;                           // R*8
    float* dTg0  = s0 + R * 8;
    float* s1    = dTg0 + BHN;
    float* dTg1  = s1 + R * 8;
    float* maxd0 = dTg1 + BHN;                   // 256
    float* maxd1 = maxd0 + 256;                  // 256
    _Float16* hp0T = (_Float16*)(maxd1 + 256);   // 32*64*512
    _Float16* hp1T = hp0T + (size_t)BB * 64 * NN;
    _Float16* W0T  = hp1T + (size_t)BB * 64 * NN;   // 64*64
    _Float16* W1T  = W0T + (size_t)64 * 64;         // 64*512
    unsigned long long* adjb = (unsigned long long*)(W1T + (size_t)64 * 512); // 16384*8B

    k_wt_prep<<<18, 256, 0, stream>>>(W0, W0T, W1, W1T);
    k_gemm0<<<1024, 256, 0, stream>>>(x, W0T, a_src0, a_dst0, adj, adjb,
                                      s0, dTg0, hp0T);
    k_maxd<<<256, 256, 0, stream>>>(dTg0, maxd0);
    k_attn_fused<0><<<1024, 256, 0, stream>>>(adjb, s0, dTg0, maxd0, hp0T,
                                              W1T, a_src1, a_dst1,
                                              s1, dTg1, hp1T, nullptr);
    k_maxd<<<256, 256, 0, stream>>>(dTg1, maxd1);
    k_attn_fused<1><<<1024, 256, 0, stream>>>(adjb, s1, dTg1, maxd1, hp1T,
                                              nullptr, nullptr, nullptr,
                                              nullptr, nullptr, nullptr, out);
}

// Round 4
// 156.937 us; speedup vs baseline: 1.1966x; 1.0177x over previous
//
#include <hip/hip_runtime.h>
#include <hip/hip_bf16.h>
#include <math.h>

#define BB 32
#define NN 512

typedef _Float16 f16x8 __attribute__((ext_vector_type(8)));
typedef __fp16  fp16x2 __attribute__((ext_vector_type(2)));
typedef float f32x4 __attribute__((ext_vector_type(4)));

#define MFMA16(a, b, c) __builtin_amdgcn_mfma_f32_16x16x32_f16(a, b, c, 0, 0, 0)

union AF { f16x8 v; unsigned int u[4]; };

// async global->LDS, 16B per lane; LDS dest = wave-uniform base + lane*16
__device__ __forceinline__ void gload_lds16(const void* g, void* l) {
    __builtin_amdgcn_global_load_lds(
        (const __attribute__((address_space(1))) unsigned int*)g,
        (__attribute__((address_space(3))) unsigned int*)l, 16, 0, 0);
}

// ============ W^T fp16 prep (W0 + W1 fused), XOR-swizzled granules =========
// Stores logical granule g of row n at physical granule g^(n&7).
__global__ __launch_bounds__(256) void k_wt_prep(
    const float* __restrict__ W0, _Float16* __restrict__ W0T,
    const float* __restrict__ W1, _Float16* __restrict__ W1T)
{
    int id = blockIdx.x * 256 + threadIdx.x;   // 0..4607
    const float* W; _Float16* WT; int KT, task;
    if (id < 512) { W = W0; WT = W0T; KT = 64;  task = id; }
    else          { W = W1; WT = W1T; KT = 512; task = id - 512; }
    int n = task & 63, gabs = task >> 6;
    int c = gabs >> 3, g = gabs & 7;
    f16x8 hv;
#pragma unroll
    for (int e = 0; e < 8; ++e)
        hv[e] = (_Float16)W[(size_t)(gabs * 8 + e) * 64 + n];
    *(f16x8*)(WT + (size_t)n * KT + c * 64 + (g ^ (n & 7)) * 8) = hv;
}

// ============ per-(b,h) max over j of dTg[b][h][j] ==========================
__global__ __launch_bounds__(256) void k_maxd(
    const float* __restrict__ dTg, float* __restrict__ maxd)
{
    __shared__ float sm[4];
    int bh = blockIdx.x;                       // 0..255
    int t = threadIdx.x, lane = t & 63, w = t >> 6;
    const float* p = dTg + (size_t)bh * NN;
    float m = fmaxf(p[t], p[t + 256]);
#pragma unroll
    for (int off = 32; off; off >>= 1) m = fmaxf(m, __shfl_xor(m, off));
    if (lane == 0) sm[w] = m;
    __syncthreads();
    if (t == 0) maxd[bh] = fmaxf(fmaxf(sm[0], sm[1]), fmaxf(sm[2], sm[3]));
}

// ============ shared epilogue: 16x66 fp32 ctile -> s, dTg, fp16 hpT =========
static __device__ __forceinline__ void epi_sd_hpt(
    const float* ctile, const float* asd_f, int row0, int t,
    float* __restrict__ s, float* __restrict__ dTg, _Float16* __restrict__ hpT)
{
    int b = row0 >> 9, jb = row0 & 511;
    if (t < 128) {
        int rr = t >> 3, h = t & 7;
        float sv = 0.f, dv = 0.f;
#pragma unroll
        for (int f = 0; f < 64; ++f) {
            float hv = ctile[rr * 66 + f];
            sv = fmaf(hv, asd_f[f * 8 + h], sv);
            dv = fmaf(hv, asd_f[512 + f * 8 + h], dv);
        }
        s[((size_t)b * NN + jb + rr) * 8 + h] = sv;
        dTg[((size_t)b * 8 + h) * NN + jb + rr] = dv;
    } else {
        int t2 = t - 128;
        int f = t2 >> 1, jl = (t2 & 1) * 8;
        f16x8 hv;
#pragma unroll
        for (int e = 0; e < 8; ++e)
            hv[e] = (_Float16)ctile[(jl + e) * 66 + f];
        *(f16x8*)(hpT + ((size_t)b * 64 + f) * NN + jb + jl) = hv;
    }
}

// ============ Layer-0 GEMM + adj bit-mask prep (vectorized) =================
__global__ __launch_bounds__(256) void k_gemm0(
    const float* __restrict__ x, const _Float16* __restrict__ W0T,
    const float* __restrict__ a_src, const float* __restrict__ a_dst,
    const float* __restrict__ adj, unsigned long long* __restrict__ adjb,
    float* __restrict__ s, float* __restrict__ dTg, _Float16* __restrict__ hpT)
{
    __shared__ float ctile[16 * 66];
    __shared__ float asd_f[1024];
    __shared__ unsigned int mrow[16][16];
    int t = threadIdx.x, row0 = blockIdx.x * 16;
    int lane = t & 63, w = t >> 6, cn = lane & 15, rq = lane >> 4;

    // ---- issue adj loads early: thread t covers row (t>>4), j in [seg*32,+32)
    int ar = t >> 4, seg = t & 15;
    const float* ap = adj + (size_t)(row0 + ar) * NN + seg * 32;
    float4 av[8];
#pragma unroll
    for (int q = 0; q < 8; ++q) av[q] = ((const float4*)ap)[q];

    ((float4*)asd_f)[t] = (t < 128) ? ((const float4*)a_src)[t]
                                    : ((const float4*)a_dst)[t - 128];
    f32x4 acc;
#pragma unroll
    for (int e = 0; e < 4; ++e) acc[e] = 0.f;
#pragma unroll
    for (int ks = 0; ks < 2; ++ks) {
        const float* xp = x + (size_t)(row0 + cn) * 64 + ks * 32 + rq * 8;
        float4 x0 = *(const float4*)xp, x1 = *(const float4*)(xp + 4);
        f16x8 ah = {(_Float16)x0.x, (_Float16)x0.y, (_Float16)x0.z, (_Float16)x0.w,
                    (_Float16)x1.x, (_Float16)x1.y, (_Float16)x1.z, (_Float16)x1.w};
        int nn = w * 16 + cn;
        f16x8 bh = *(const f16x8*)(W0T + (size_t)nn * 64 + (((ks * 4 + rq) ^ (nn & 7)) * 8));
        acc = MFMA16(ah, bh, acc);
    }
#pragma unroll
    for (int r = 0; r < 4; ++r)
        ctile[(rq * 4 + r) * 66 + w * 16 + cn] = acc[r];
    __syncthreads();
    epi_sd_hpt(ctile, asd_f, row0, t, s, dTg, hpT);

    // ---- pack 32 adj entries -> u32 bits, fold self-loop, assemble u64s
    unsigned int m32 = 0;
#pragma unroll
    for (int q = 0; q < 8; ++q) {
        if (av[q].x != 0.f) m32 |= 1u << (q * 4 + 0);
        if (av[q].y != 0.f) m32 |= 1u << (q * 4 + 1);
        if (av[q].z != 0.f) m32 |= 1u << (q * 4 + 2);
        if (av[q].w != 0.f) m32 |= 1u << (q * 4 + 3);
    }
    int i = (row0 + ar) & (NN - 1);
    if ((i >> 5) == seg) m32 |= 1u << (i & 31);
    mrow[ar][seg] = m32;
    __syncthreads();
    if (t < 128) {
        int r = t >> 3, k = t & 7;
        unsigned long long u = (unsigned long long)mrow[r][2 * k]
                             | ((unsigned long long)mrow[r][2 * k + 1] << 32);
        adjb[(size_t)(row0 + r) * 8 + k] = u;
    }
}

// ============ fused attention v8 ============================================
// Super-chunk staging: per 128-j window, global_load_lds stages two hT tiles
// (8KB each) AND the dd slice (fp32 [8][128], 4KB) into a 20KB buffer,
// double-buffered (40KB LDS, still 4 blocks/CU). Hot loop reads dd from LDS
// (broadcast, conflict-free) -> zero per-lane global loads, barriers 9 -> 5.
// gemm1: B-fragments read direct from L2-resident W1T, zero-barrier K-loop.
#define PSTEP(DD0v, DD1v, MBYTE, KS, HTC)                               \
    do {                                                                \
        AF aA, aB;                                                      \
        _Pragma("unroll")                                               \
        for (int e = 0; e < 8; e += 2) {                                \
            float pA[2], pB[2];                                         \
            _Pragma("unroll")                                           \
            for (int q = 0; q < 2; ++q) {                               \
                int ee = e + q;                                         \
                bool con = (MBYTE >> ee) & 1u;                          \
                float e0 = sv0 + DD0v[ee];                              \
                float l0 = fmaxf(e0, 0.2f * e0);                        \
                float p0 = __expf(l0 - M0);                             \
                pA[q] = (con && l0 != 0.f) ? p0 : 0.f;                  \
                float e1 = sv1 + DD1v[ee];                              \
                float l1 = fmaxf(e1, 0.2f * e1);                        \
                float p1 = __expf(l1 - M1);                             \
                pB[q] = (con && l1 != 0.f) ? p1 : 0.f;                  \
            }                                                           \
            fp16x2 ka = __builtin_amdgcn_cvt_pkrtz(pA[0], pA[1]);       \
            fp16x2 kb = __builtin_amdgcn_cvt_pkrtz(pB[0], pB[1]);       \
            aA.u[e >> 1] = __builtin_bit_cast(unsigned int, ka);        \
            aB.u[e >> 1] = __builtin_bit_cast(unsigned int, kb);        \
        }                                                               \
        accrs[0] = MFMA16(aA.v, ones, accrs[0]);                        \
        accrs[1] = MFMA16(aB.v, ones, accrs[1]);                        \
        _Pragma("unroll")                                               \
        for (int ft = 0; ft < 4; ++ft) {                                \
            int f = ft * 16 + cn;                                       \
            f16x8 bh = *(const f16x8*)&HTC[f * 64 + ((((KS) * 4 + rq) ^ (f & 7)) * 8)]; \
            acc[0][ft] = MFMA16(aA.v, bh, acc[0][ft]);                  \
            acc[1][ft] = MFMA16(aB.v, bh, acc[1][ft]);                  \
        }                                                               \
    } while (0)

// stage super-chunk SC (128 j) into buffer B: hT tile0 @+0, tile1 @+8192,
// dd [8][128] fp32 @+16384. Per wave: 5x gload_lds16.
#define STAGE_SC(SC, B)                                                  \
    do {                                                                 \
        _Float16* t0_ = (_Float16*)(B) + (w << 9);                       \
        _Float16* t1_ = (_Float16*)((B) + 8192) + (w << 9);              \
        gload_lds16(src0 + (SC) * 128, t0_);                             \
        gload_lds16(src1 + (SC) * 128, t0_ + 2048);                      \
        gload_lds16(src0 + (SC) * 128 + 64, t1_);                        \
        gload_lds16(src1 + (SC) * 128 + 64, t1_ + 2048);                 \
        gload_lds16(dsrc + (SC) * 128, (float*)((B) + 16384) + (w << 8));\
    } while (0)

template<int MODE>
__global__ __launch_bounds__(256, 4) void k_attn_fused(
    const unsigned long long* __restrict__ adjb, const float* __restrict__ s,
    const float* __restrict__ dTg, const float* __restrict__ maxd,
    const _Float16* __restrict__ hpT,
    const _Float16* __restrict__ W1T,
    const float* __restrict__ a_src, const float* __restrict__ a_dst,
    float* __restrict__ s_out, float* __restrict__ dTg_out,
    _Float16* __restrict__ hpT_out, float* __restrict__ o_f)
{
    __shared__ __align__(16) char smem[40960];

    int blk = blockIdx.x;
    int vb = ((blk & 7) << 7) | (blk >> 3);    // XCD swizzle: 4 batches/XCD
    int b = vb >> 5, i0 = (vb & 31) << 4;
    int row0 = vb * 16;                        // = b*512 + i0
    int t = threadIdx.x, lane = t & 63, w = t >> 6;
    int cn = lane & 15, rq = lane >> 4;
    int h0 = 2 * w, h1 = h0 + 1;
    int myrow = i0 + cn;

    const _Float16* hb = hpT + (size_t)b * 64 * NN;
    // hT staging: source pre-swizzled (granule g0^(f&7)), LDS linear
    int f0 = t >> 3, g0 = t & 7;               // f0 in [0,32)
    const _Float16* src0 = hb + (size_t)f0 * NN + ((g0 ^ (f0 & 7)) * 8);
    const _Float16* src1 = hb + (size_t)(f0 + 32) * NN + ((g0 ^ (f0 & 7)) * 8);
    // dd staging: wave w stages heads 2w,2w+1; lane covers 4 floats
    const float* dgB = dTg + (size_t)b * 8 * NN;
    int hs = h0 + (lane >> 5), js = (lane & 31) * 4;
    const float* dsrc = dgB + (size_t)hs * NN + js;

    char* bufP = smem;
    char* bufQ = smem + 20480;

    STAGE_SC(0, bufP);                         // prologue staging in flight

    float sv0 = s[((size_t)b * NN + myrow) * 8 + h0];
    float sv1 = s[((size_t)b * NN + myrow) * 8 + h1];
    float M0 = fmaxf(sv0 + maxd[b * 8 + h0], 0.f);
    float M1 = fmaxf(sv1 + maxd[b * 8 + h1], 0.f);
    const unsigned long long* abr = adjb + ((size_t)b * NN + myrow) * 8;
    int rq8 = rq * 8;
    unsigned long long mb0 = abr[0], mb1 = abr[1];

    f16x8 ones;
#pragma unroll
    for (int e = 0; e < 8; ++e) ones[e] = (_Float16)1.0f;

    f32x4 acc[2][4], accrs[2];
#pragma unroll
    for (int hh = 0; hh < 2; ++hh) {
#pragma unroll
        for (int e = 0; e < 4; ++e) accrs[hh][e] = 0.f;
#pragma unroll
        for (int ft = 0; ft < 4; ++ft)
#pragma unroll
            for (int e = 0; e < 4; ++e) acc[hh][ft][e] = 0.f;
    }

    __syncthreads();                           // buf0 staged

    for (int sc = 0; sc < 4; ++sc) {
        char* cur = (sc & 1) ? bufQ : bufP;
        char* nxt = (sc & 1) ? bufP : bufQ;
        if (sc < 3) STAGE_SC(sc + 1, nxt);     // lands during this sc's compute
        unsigned long long nm0 = 0, nm1 = 0;
        if (sc < 3) { nm0 = abr[2 * sc + 2]; nm1 = abr[2 * sc + 3]; }
        const float* ddl0 = (const float*)(cur + 16384) + h0 * 128;
        const float* ddl1 = ddl0 + 128;
#pragma unroll
        for (int half = 0; half < 2; ++half) {
            unsigned long long mbc = half ? mb1 : mb0;
            unsigned int ml = (unsigned int)mbc, mh = (unsigned int)(mbc >> 32);
            const _Float16* hTc = (const _Float16*)(cur + half * 8192);
#pragma unroll
            for (int ks = 0; ks < 2; ++ks) {
                int jrel = half * 64 + ks * 32 + rq8;
                unsigned int mby = ((ks ? mh : ml) >> rq8) & 0xffu;
                float dd0[8], dd1[8];
                *(float4*)&dd0[0] = *(const float4*)(ddl0 + jrel);
                *(float4*)&dd0[4] = *(const float4*)(ddl0 + jrel + 4);
                *(float4*)&dd1[0] = *(const float4*)(ddl1 + jrel);
                *(float4*)&dd1[4] = *(const float4*)(ddl1 + jrel + 4);
                PSTEP(dd0, dd1, mby, ks, hTc);
            }
        }
        mb0 = nm0; mb1 = nm1;
        __syncthreads();                       // drains next-sc staging too
    }

    float invr[2][4];
#pragma unroll
    for (int hh = 0; hh < 2; ++hh)
#pragma unroll
        for (int r = 0; r < 4; ++r) invr[hh][r] = 1.0f / accrs[hh][r];

    if (MODE == 0) {
        // ---- x1 tiles (normalized + ELU) into LDS, A-layout, XOR-swizzled
        _Float16* x1all = (_Float16*)(smem + 16384);   // [8 heads][16*64], 16KB
#pragma unroll
        for (int hh = 0; hh < 2; ++hh) {
            int h = h0 + hh;
#pragma unroll
            for (int ft = 0; ft < 4; ++ft)
#pragma unroll
                for (int r = 0; r < 4; ++r) {
                    int il = rq * 4 + r;
                    float v = acc[hh][ft][r] * invr[hh][r];
                    v = v > 0.f ? v : __expf(v) - 1.f;   // ELU
                    int f = ft * 16 + cn;
                    x1all[h * 1024 + il * 64 + (((f >> 3) ^ (il & 7)) * 8) + (f & 7)] =
                        (_Float16)v;
                }
        }
        __syncthreads();   // x1all visible
        // ---- gemm1: A from LDS x1all, B direct from L2-resident W1T.
        // Zero barriers; compiler pipelines 16 indep dwordx4 against 16 MFMA.
        f32x4 g1;
#pragma unroll
        for (int e = 0; e < 4; ++e) g1[e] = 0.f;
        int nn = w * 16 + cn;
        const _Float16* wb = W1T + (size_t)nn * 512;
#pragma unroll
        for (int kc = 0; kc < 8; ++kc) {
#pragma unroll
            for (int ks = 0; ks < 2; ++ks) {
                f16x8 ah = *(const f16x8*)&x1all[kc * 1024 + cn * 64 +
                                                 (((ks * 4 + rq) ^ (cn & 7)) * 8)];
                f16x8 bh = *(const f16x8*)(wb + kc * 64 +
                                           (((ks * 4 + rq) ^ (nn & 7)) * 8));
                g1 = MFMA16(ah, bh, g1);
            }
        }
        __syncthreads();                       // x1all reads done before reuse
        float* ctile = (float*)(smem + 16384); // 4224 B (x1all dead)
        float* asd_f = (float*)(smem + 24576); // 4096 B
#pragma unroll
        for (int r = 0; r < 4; ++r)
            ctile[(rq * 4 + r) * 66 + w * 16 + cn] = g1[r];
        ((float4*)asd_f)[t] = (t < 128) ? ((const float4*)a_src)[t]
                                        : ((const float4*)a_dst)[t - 128];
        __syncthreads();
        epi_sd_hpt(ctile, asd_f, row0, t, s_out, dTg_out, hpT_out);
    } else {
        float* red = (float*)smem;             // [4][16][64] fp32 = 16 KB
#pragma unroll
        for (int ft = 0; ft < 4; ++ft)
#pragma unroll
            for (int r = 0; r < 4; ++r) {
                int il = rq * 4 + r;
                float v = acc[0][ft][r] * invr[0][r]
                        + acc[1][ft][r] * invr[1][r];
                red[(w * 16 + il) * 64 + ft * 16 + cn] = v;
            }
        __syncthreads();
#pragma unroll
        for (int u = 0; u < 4; ++u) {
            int idx = t + u * 256;
            int il = idx >> 6, f = idx & 63;
            float sum = red[il * 64 + f] + red[(16 + il) * 64 + f]
                      + red[(32 + il) * 64 + f] + red[(48 + il) * 64 + f];
            o_f[((size_t)b * NN + i0 + il) * 64 + f] = sum * 0.125f;
        }
    }
}

extern "C" void kernel_launch(void* const* d_in, const int* in_sizes, int n_in,
                              void* d_out, int out_size, void* d_ws, size_t ws_size,
                              hipStream_t stream) {
    const float* x      = (const float*)d_in[0];
    const float* adj    = (const float*)d_in[1];
    const float* W0     = (const float*)d_in[4];
    const float* a_src0 = (const float*)d_in[5];
    const float* a_dst0 = (const float*)d_in[6];
    const float* W1     = (const float*)d_in[7];
    const float* a_src1 = (const float*)d_in[8];
    const float* a_dst1 = (const float*)d_in[9];
    float* out = (float*)d_out;

    float* ws = (float*)d_ws;
    const size_t R = (size_t)BB * NN;            // 16384 rows
    const size_t BHN = (size_t)BB * 8 * NN;      // 131072
    float* s0    = ws;                           // R*8
    float* dTg0  = s0 + R * 8;
    float* s1    = dTg0 + BHN;
    float* dTg1  = s1 + R * 8;
    float* maxd0 = dTg1 + BHN;                   // 256
    float* maxd1 = maxd0 + 256;                  // 256
    _Float16* hp0T = (_Float16*)(maxd1 + 256);   // 32*64*512
    _Float16* hp1T = hp0T + (size_t)BB * 64 * NN;
    _Float16* W0T  = hp1T + (size_t)BB * 64 * NN;   // 64*64
    _Float16* W1T  = W0T + (size_t)64 * 64;         // 64*512
    unsigned long long* adjb = (unsigned long long*)(W1T + (size_t)64 * 512); // 16384*8B

    k_wt_prep<<<18, 256, 0, stream>>>(W0, W0T, W1, W1T);
    k_gemm0<<<1024, 256, 0, stream>>>(x, W0T, a_src0, a_dst0, adj, adjb,
                                      s0, dTg0, hp0T);
    k_maxd<<<256, 256, 0, stream>>>(dTg0, maxd0);
    k_attn_fused<0><<<1024, 256, 0, stream>>>(adjb, s0, dTg0, maxd0, hp0T,
                                              W1T, a_src1, a_dst1,
                                              s1, dTg1, hp1T, nullptr);
    k_maxd<<<256, 256, 0, stream>>>(dTg1, maxd1);
    k_attn_fused<1><<<1024, 256, 0, stream>>>(adjb, s1, dTg1, maxd1, hp1T,
                                              nullptr, nullptr, nullptr,
                                              nullptr, nullptr, nullptr, out);
}